// Round 7
// baseline (32.943 us; speedup 1.0000x reference)
//
#include <hip/hip_runtime.h>

#define T_IN 2048
#define UPSCALE 480
#define T_OUT (T_IN * UPSCALE)   // 983040
#define BPB 64                    // blocks per batch
#define CHUNK (T_OUT / BPB)       // 15360 outputs per block
#define NTHREADS 256
#define ITERS (CHUNK / 4 / NTHREADS)  // 15 float4 groups per thread
#define NINTERVAL (T_IN - 1)      // 2047

typedef float floatx4 __attribute__((ext_vector_type(4)));

__device__ __forceinline__ float signf(float x) {
    return (x > 0.f) ? 1.f : ((x < 0.f) ? -1.f : 0.f);
}

// Fritsch-Carlson edge slope (matches reference edge())
__device__ __forceinline__ float edge_slope(float dA, float dB) {
    float d = (3.f * dA - dB) * 0.5f;
    if (signf(d) != signf(dA)) {
        d = 0.f;
    } else if ((signf(dA) != signf(dB)) && (fabsf(d) > 3.f * fabsf(dA))) {
        d = 3.f * dA;
    }
    return d;
}

__device__ __forceinline__ float interior_slope(float dl, float dr) {
    float p = dl * dr;
    return (p > 0.f) ? (2.f * p / (dl + dr)) : 0.f;
}

// R4 structure (best known: 25.8 us) + ONE change: nontemporal float4 stores.
// Output stream (125.8 MB) is 4x aggregate L2 -> write-allocate thrash;
// nt stores stream past L2.
__global__ __launch_bounds__(NTHREADS) void pchip_upsample_kernel(
    const float* __restrict__ x, float* __restrict__ out)
{
    const int b   = blockIdx.y;
    const int cb  = blockIdx.x;
    const int tid = threadIdx.x;

    const float STEP = (float)(T_IN - 1) / (float)(T_OUT - 1);
    const float* __restrict__ y = x + (size_t)b * T_IN;

    floatx4* outv = (floatx4*)(out + (size_t)b * T_OUT + (size_t)cb * CHUNK);
    const int jbase = cb * CHUNK;

    #pragma unroll 3
    for (int it = 0; it < ITERS; ++it) {
        const int g  = it * NTHREADS + tid;   // float4 group index within chunk
        const int j0 = jbase + g * 4;         // output index within batch

        float t0 = (float)j0 * STEP;
        int idx = (int)t0;
        idx = idx > (NINTERVAL - 1) ? (NINTERVAL - 1) : idx;
        float s0 = t0 - (float)idx;

        const int im1 = (idx > 0) ? idx - 1 : 0;
        const int ip2 = (idx < T_IN - 2) ? idx + 2 : T_IN - 1;

        // near-broadcast loads, L1/L2-resident
        float ym1 = y[im1];
        float y0  = y[idx];
        float y1  = y[idx + 1];
        float y2  = y[ip2];

        float dl = y0 - ym1;   // delta[idx-1]
        float dc = y1 - y0;    // delta[idx]
        float dr = y2 - y1;    // delta[idx+1]

        float d0 = interior_slope(dl, dc);
        if (idx == 0) d0 = edge_slope(dc, dr);
        float d1 = interior_slope(dc, dr);
        if (idx == NINTERVAL - 1) d1 = edge_slope(dc, dl);

        // v(s) = c0 + c1*s + c2*s^2 + c3*s^3
        float c0 = y0;
        float c1 = d0;
        float c2 = __builtin_fmaf(3.f, dc, -2.f * d0) - d1;
        float c3 = (d0 + d1) - 2.f * dc;

        floatx4 r;
        float s = s0;
        r.x = __builtin_fmaf(__builtin_fmaf(__builtin_fmaf(c3, s, c2), s, c1), s, c0); s += STEP;
        r.y = __builtin_fmaf(__builtin_fmaf(__builtin_fmaf(c3, s, c2), s, c1), s, c0); s += STEP;
        r.z = __builtin_fmaf(__builtin_fmaf(__builtin_fmaf(c3, s, c2), s, c1), s, c0); s += STEP;
        r.w = __builtin_fmaf(__builtin_fmaf(__builtin_fmaf(c3, s, c2), s, c1), s, c0);

        __builtin_nontemporal_store(r, &outv[g]);
    }
}

extern "C" void kernel_launch(void* const* d_in, const int* in_sizes, int n_in,
                              void* d_out, int out_size, void* d_ws, size_t ws_size,
                              hipStream_t stream) {
    (void)d_ws; (void)ws_size; (void)n_in; (void)out_size;
    const float* x = (const float*)d_in[0];
    float* out = (float*)d_out;
    const int B = in_sizes[0] / T_IN;  // 32

    dim3 grid(BPB, B);
    pchip_upsample_kernel<<<grid, NTHREADS, 0, stream>>>(x, out);
}

// Round 8
// 25.644 us; speedup vs baseline: 1.2846x; 1.2846x over previous
//
#include <hip/hip_runtime.h>

#define T_IN 2048
#define UPSCALE 480
#define T_OUT (T_IN * UPSCALE)   // 983040
#define BPB 64                    // blocks per batch
#define CHUNK (T_OUT / BPB)       // 15360 outputs per block
#define NTHREADS 256
#define ITERS (CHUNK / 4 / NTHREADS)  // 15 float4 groups per thread
#define NINTERVAL (T_IN - 1)      // 2047

__device__ __forceinline__ float signf(float x) {
    return (x > 0.f) ? 1.f : ((x < 0.f) ? -1.f : 0.f);
}

// Fritsch-Carlson edge slope (matches reference edge())
__device__ __forceinline__ float edge_slope(float dA, float dB) {
    float d = (3.f * dA - dB) * 0.5f;
    if (signf(d) != signf(dA)) {
        d = 0.f;
    } else if ((signf(dA) != signf(dB)) && (fabsf(d) > 3.f * fabsf(dA))) {
        d = 3.f * dA;
    }
    return d;
}

// Harmonic-mean interior slope via fast v_rcp_f32 (rel err ~1e-7).
// Safe: p>0 => (a+b)^2 >= 4p (AM-GM), so the rcp argument is bounded
// away from 0/denormal relative to p.
__device__ __forceinline__ float interior_slope(float a, float b) {
    float p = a * b;
    float r = __builtin_amdgcn_rcpf(a + b);
    return (p > 0.f) ? 2.f * p * r : 0.f;
}

// R4 structure (best known: 25.8 us) + ONE change: exact divides ->
// v_rcp_f32 (cuts ~20 VALU instrs/group of div expansion).
__global__ __launch_bounds__(NTHREADS) void pchip_upsample_kernel(
    const float* __restrict__ x, float* __restrict__ out)
{
    const int b   = blockIdx.y;
    const int cb  = blockIdx.x;
    const int tid = threadIdx.x;

    const float STEP = (float)(T_IN - 1) / (float)(T_OUT - 1);
    const float* __restrict__ y = x + (size_t)b * T_IN;

    float4* outv = (float4*)(out + (size_t)b * T_OUT + (size_t)cb * CHUNK);
    const int jbase = cb * CHUNK;

    #pragma unroll 3
    for (int it = 0; it < ITERS; ++it) {
        const int g  = it * NTHREADS + tid;   // float4 group index within chunk
        const int j0 = jbase + g * 4;         // output index within batch

        float t0 = (float)j0 * STEP;
        int idx = (int)t0;
        idx = idx > (NINTERVAL - 1) ? (NINTERVAL - 1) : idx;
        float s0 = t0 - (float)idx;

        const int im1 = (idx > 0) ? idx - 1 : 0;
        const int ip2 = (idx < T_IN - 2) ? idx + 2 : T_IN - 1;

        // near-broadcast loads, L1/L2-resident
        float ym1 = y[im1];
        float y0  = y[idx];
        float y1  = y[idx + 1];
        float y2  = y[ip2];

        float dl = y0 - ym1;   // delta[idx-1]
        float dc = y1 - y0;    // delta[idx]
        float dr = y2 - y1;    // delta[idx+1]

        float d0 = interior_slope(dl, dc);
        if (idx == 0) d0 = edge_slope(dc, dr);
        float d1 = interior_slope(dc, dr);
        if (idx == NINTERVAL - 1) d1 = edge_slope(dc, dl);

        // v(s) = c0 + c1*s + c2*s^2 + c3*s^3
        float c0 = y0;
        float c1 = d0;
        float c2 = __builtin_fmaf(3.f, dc, -2.f * d0) - d1;
        float c3 = (d0 + d1) - 2.f * dc;

        float4 r;
        float s = s0;
        r.x = __builtin_fmaf(__builtin_fmaf(__builtin_fmaf(c3, s, c2), s, c1), s, c0); s += STEP;
        r.y = __builtin_fmaf(__builtin_fmaf(__builtin_fmaf(c3, s, c2), s, c1), s, c0); s += STEP;
        r.z = __builtin_fmaf(__builtin_fmaf(__builtin_fmaf(c3, s, c2), s, c1), s, c0); s += STEP;
        r.w = __builtin_fmaf(__builtin_fmaf(__builtin_fmaf(c3, s, c2), s, c1), s, c0);

        outv[g] = r;
    }
}

extern "C" void kernel_launch(void* const* d_in, const int* in_sizes, int n_in,
                              void* d_out, int out_size, void* d_ws, size_t ws_size,
                              hipStream_t stream) {
    (void)d_ws; (void)ws_size; (void)n_in; (void)out_size;
    const float* x = (const float*)d_in[0];
    float* out = (float*)d_out;
    const int B = in_sizes[0] / T_IN;  // 32

    dim3 grid(BPB, B);
    pchip_upsample_kernel<<<grid, NTHREADS, 0, stream>>>(x, out);
}